// Round 2
// 410.672 us; speedup vs baseline: 1.1428x; 1.1428x over previous
//
#include <hip/hip_runtime.h>
#include <math.h>

#define N_TOT 32768
#define M_NBR 12
#define ORIG  92
#define EDGE  41
#define FD    128
#define HD    256
#define APC   256
#define NCRY  128

#define STR   136          // inter_s row stride in bf16
#define PCS   132          // phic_s row stride in floats
#define WF_PER_LAYER 73728 // bf16 elems of swizzled conv weight frags per layer
#define WF_EMBED     12288 // 3 ktiles x 8 ntiles x 64 x 8
#define WF_H         32768 // 4 ktiles x 16 ntiles x 64 x 8

typedef __attribute__((ext_vector_type(8))) short bf16x8;
typedef __attribute__((ext_vector_type(4))) float f32x4;

union BF8 { bf16x8 v; unsigned u[4]; };

__device__ __forceinline__ unsigned pk2(float lo, float hi) {
    unsigned r;
    asm("v_cvt_pk_bf16_f32 %0, %1, %2" : "=v"(r) : "v"(lo), "v"(hi));
    return r;
}
__device__ __forceinline__ short f2bf(float f) { return (short)pk2(f, f); }
__device__ __forceinline__ float bf2f(short s) {
    union { unsigned u; float f; } v; v.u = ((unsigned)(unsigned short)s) << 16;
    return v.f;
}
__device__ __forceinline__ float softplus_f(float x) {
    return fmaxf(x, 0.0f) + 0.6931471805599453f * __log2f(1.0f + __expf(-fabsf(x)));
}
__device__ __forceinline__ float sigmoid_f(float x) {
    return __builtin_amdgcn_rcpf(1.0f + __expf(-x));
}

// ---------------- weight pre-swizzle into B-fragment order ----------------
// B-frag: for (kt,nt): lane l holds W[kt*32 + (l>>4)*8 + j][nt*16 + (l&15)], j=0..7
// (identical bytes serve as the A-fragment of W^T for the swapped-operand MFMAs)
__global__ __launch_bounds__(256) void swizzle_kernel(
    const float* __restrict__ Wc_all, const float* __restrict__ Wn_all,
    const float* __restrict__ We_all, const float* __restrict__ Wg_all,
    const float* __restrict__ Wm_all, const float* __restrict__ W_embed,
    const float* __restrict__ W_h, short* __restrict__ dst_all)
{
    int gid = blockIdx.x * 256 + threadIdx.x;
    if (gid >= 33280) return;
    const float* W; short* dst; int K_real, fid, stride, l, nt, kt;
    if (gid < 27648) {
        int layer = gid / 9216;
        int rem = gid - layer * 9216;
        short* dbase = dst_all + layer * WF_PER_LAYER;
        if (rem < 2048)      { W = Wc_all + layer * 16384; dst = dbase;         K_real = 128; fid = rem; }
        else if (rem < 4096) { W = Wn_all + layer * 16384; dst = dbase + 16384; K_real = 128; fid = rem - 2048; }
        else if (rem < 5120) { W = We_all + layer * 5248;  dst = dbase + 32768; K_real = 41;  fid = rem - 4096; }
        else if (rem < 7168) { W = Wg_all + layer * 16384; dst = dbase + 40960; K_real = 128; fid = rem - 5120; }
        else                 { W = Wm_all + layer * 16384; dst = dbase + 57344; K_real = 128; fid = rem - 7168; }
        stride = 128; l = fid & 63; nt = (fid >> 6) & 7; kt = fid >> 9;
    } else if (gid < 29184) {
        fid = gid - 27648;
        W = W_embed; dst = dst_all + 3 * WF_PER_LAYER; K_real = ORIG; stride = 128;
        l = fid & 63; nt = (fid >> 6) & 7; kt = fid >> 9;
    } else {
        fid = gid - 29184;
        W = W_h; dst = dst_all + 3 * WF_PER_LAYER + WF_EMBED; K_real = 128; stride = 256;
        l = fid & 63; nt = (fid >> 6) & 15; kt = fid >> 10;
    }
    int n = nt * 16 + (l & 15), kb = kt * 32 + (l >> 4) * 8;
    bf16x8 v;
    #pragma unroll
    for (int j = 0; j < 8; ++j) {
        int k = kb + j;
        v[j] = (k < K_real) ? f2bf(W[k * stride + n]) : (short)0;
    }
    *(bf16x8*)(dst + fid * 8) = v;
}

// ---------------- embed MFMA (swapped operands): 64 atoms/block, 4 waves ----------------
__global__ __launch_bounds__(256) void embed_mfma_kernel(
    const float* __restrict__ atom_fea, const short* __restrict__ wef,
    const float* __restrict__ b, float* __restrict__ x, short* __restrict__ xbf)
{
    const int tid = threadIdx.x;
    const int w = tid >> 6, lane = tid & 63;
    const int q = lane >> 4, m = lane & 15;
    const int a0 = blockIdx.x * 64;
    const int arow = a0 + w * 16 + m;

    // x^T B-fragments: atom_fea row (fp32 -> bf16 via cvt_pk), K padded 92 -> 96
    BF8 aA[3];
    const float* ap = atom_fea + (long)arow * ORIG;
    #pragma unroll
    for (int kt = 0; kt < 3; ++kt) {
        const int kb = kt * 32 + q * 8;
        BF8 t;
        if (kb + 7 < ORIG) {
            const float4 u0 = *(const float4*)(ap + kb);
            const float4 u1 = *(const float4*)(ap + kb + 4);
            t.u[0] = pk2(u0.x, u0.y); t.u[1] = pk2(u0.z, u0.w);
            t.u[2] = pk2(u1.x, u1.y); t.u[3] = pk2(u1.z, u1.w);
        } else {
            // kt=2, q=3: kb=88, only 88..91 valid
            const float4 u0 = *(const float4*)(ap + kb);
            t.u[0] = pk2(u0.x, u0.y); t.u[1] = pk2(u0.z, u0.w);
            t.u[2] = 0u; t.u[3] = 0u;
        }
        aA[kt] = t;
    }

    #pragma unroll
    for (int ct = 0; ct < 8; ++ct) {
        f32x4 C = {0.f, 0.f, 0.f, 0.f};
        #pragma unroll
        for (int kt = 0; kt < 3; ++kt)
            C = __builtin_amdgcn_mfma_f32_16x16x32_bf16(
                    *(const bf16x8*)(wef + ((kt * 8 + ct) * 64 + lane) * 8), aA[kt].v, C, 0, 0, 0);
        // C[r] = x[arow][ct*16 + q*4 + r]
        const float4 bv = *(const float4*)(b + ct * 16 + q * 4);
        const float o0 = C[0] + bv.x, o1 = C[1] + bv.y, o2 = C[2] + bv.z, o3 = C[3] + bv.w;
        const long base = ((long)arow << 7) + ct * 16 + q * 4;
        *(float4*)(x + base) = make_float4(o0, o1, o2, o3);
        *(uint2*)(xbf + base) = make_uint2(pk2(o0, o1), pk2(o2, o3));
    }
}

// ---------------- fused MFMA conv layer: 16 atoms / block, 4 waves ----------------
// All MFMAs use swapped operands: mfma(W_frag, x_frag, C) computes phi^T, so each
// lane's C holds ONE row x FOUR consecutive cols -> b64 LDS writes, float4 phic reads.
__global__ __launch_bounds__(256) void conv_mfma_kernel(
    const float* __restrict__ x_in, const short* __restrict__ xbf_in,
    float* __restrict__ x_out, short* __restrict__ xbf_out,
    const float* __restrict__ nbr_fea, const int* __restrict__ nbr_idx,
    const short* __restrict__ wf,
    const float* __restrict__ bc, const float* __restrict__ bn,
    const float* __restrict__ be, const float* __restrict__ bg,
    const float* __restrict__ bm,
    const float* __restrict__ lns, const float* __restrict__ lnb)
{
    __shared__ short inter_s[192 * STR];
    __shared__ float phic_s[16 * PCS];
    __shared__ int   idx_s[192];

    const int tid = threadIdx.x;
    const int w = tid >> 6, lane = tid & 63;
    const int q = lane >> 4, m = lane & 15;
    const int a0 = blockIdx.x * 16;
    const long r0 = (long)a0 * M_NBR;

    const short* Wc = wf;
    const short* Wn = wf + 16384;
    const short* We = wf + 32768;
    const short* Wg = wf + 40960;
    const short* Wm = wf + 57344;

    if (tid < 192) idx_s[tid] = nbr_idx[r0 + tid];

    // phase 0: phi_c -> phic_s[atom][col], float4 writes
    {
        bf16x8 aC[4];
        #pragma unroll
        for (int kt = 0; kt < 4; ++kt)
            aC[kt] = *(const bf16x8*)(xbf_in + ((long)(a0 + m) << 7) + kt * 32 + q * 8);
        #pragma unroll
        for (int ii = 0; ii < 2; ++ii) {
            const int ct = w * 2 + ii;
            f32x4 C = {0.f, 0.f, 0.f, 0.f};
            #pragma unroll
            for (int kt = 0; kt < 4; ++kt)
                C = __builtin_amdgcn_mfma_f32_16x16x32_bf16(
                        *(const bf16x8*)(Wc + ((kt * 8 + ct) * 64 + lane) * 8), aC[kt], C, 0, 0, 0);
            const float4 bv = *(const float4*)(bc + ct * 16 + q * 4);
            *(float4*)(phic_s + m * PCS + ct * 16 + q * 4) =
                make_float4(C[0] + bv.x, C[1] + bv.y, C[2] + bv.z, C[3] + bv.w);
        }
    }
    __syncthreads();

    // neighbor-atom fragments (gathered rows of xbf)
    bf16x8 aN[3][4];
    #pragma unroll
    for (int i = 0; i < 3; ++i) {
        const int row = (w * 3 + i) * 16 + m;
        const long g = (long)idx_s[row] << 7;
        #pragma unroll
        for (int kt = 0; kt < 4; ++kt)
            aN[i][kt] = *(const bf16x8*)(xbf_in + g + kt * 32 + q * 8);
    }
    // edge fragments via cvt_pk
    bf16x8 aE[3][2];
    #pragma unroll
    for (int i = 0; i < 3; ++i) {
        const int row = (w * 3 + i) * 16 + m;
        const float* ep = nbr_fea + (r0 + row) * EDGE;
        BF8 e0, e1;
        const int kb = q * 8;
        e0.u[0] = pk2(ep[kb + 0], ep[kb + 1]);
        e0.u[1] = pk2(ep[kb + 2], ep[kb + 3]);
        e0.u[2] = pk2(ep[kb + 4], ep[kb + 5]);
        e0.u[3] = pk2(ep[kb + 6], ep[kb + 7]);
        e1.u[0] = 0u; e1.u[1] = 0u; e1.u[2] = 0u; e1.u[3] = 0u;
        if (q == 0) {
            e1.u[0] = pk2(ep[32], ep[33]);
            e1.u[1] = pk2(ep[34], ep[35]);
            e1.u[2] = pk2(ep[36], ep[37]);
            e1.u[3] = pk2(ep[38], ep[39]);
        } else if (q == 1) {
            e1.u[0] = pk2(ep[40], 0.0f);
        }
        aE[i][0] = e0.v; aE[i][1] = e1.v;
    }

    // atom index is fixed per i now (row depends only on i,m)
    int atomL[3];
    #pragma unroll
    for (int i = 0; i < 3; ++i)
        atomL[i] = (w * 48 + i * 16 + m) / 12;

    // phase 1: inter = phi_c * phi_n * phi_e  (transposed C-layout)
    #pragma unroll
    for (int ct = 0; ct < 8; ++ct) {
        f32x4 Cn[3], Ce[3];
        #pragma unroll
        for (int i = 0; i < 3; ++i) {
            Cn[i] = (f32x4){0.f, 0.f, 0.f, 0.f};
            Ce[i] = (f32x4){0.f, 0.f, 0.f, 0.f};
        }
        #pragma unroll
        for (int kt = 0; kt < 4; ++kt) {
            const bf16x8 nfr = *(const bf16x8*)(Wn + ((kt * 8 + ct) * 64 + lane) * 8);
            #pragma unroll
            for (int i = 0; i < 3; ++i)
                Cn[i] = __builtin_amdgcn_mfma_f32_16x16x32_bf16(nfr, aN[i][kt], Cn[i], 0, 0, 0);
        }
        #pragma unroll
        for (int kt = 0; kt < 2; ++kt) {
            const bf16x8 efr = *(const bf16x8*)(We + ((kt * 8 + ct) * 64 + lane) * 8);
            #pragma unroll
            for (int i = 0; i < 3; ++i)
                Ce[i] = __builtin_amdgcn_mfma_f32_16x16x32_bf16(efr, aE[i][kt], Ce[i], 0, 0, 0);
        }
        const float4 bnv = *(const float4*)(bn + ct * 16 + q * 4);
        const float4 bev = *(const float4*)(be + ct * 16 + q * 4);
        #pragma unroll
        for (int i = 0; i < 3; ++i) {
            const float4 pc = *(const float4*)(phic_s + atomL[i] * PCS + ct * 16 + q * 4);
            const float v0 = pc.x * (Cn[i][0] + bnv.x) * (Ce[i][0] + bev.x);
            const float v1 = pc.y * (Cn[i][1] + bnv.y) * (Ce[i][1] + bev.y);
            const float v2 = pc.z * (Cn[i][2] + bnv.z) * (Ce[i][2] + bev.z);
            const float v3 = pc.w * (Cn[i][3] + bnv.w) * (Ce[i][3] + bev.w);
            *(uint2*)(inter_s + (w * 48 + i * 16 + m) * STR + ct * 16 + q * 4) =
                make_uint2(pk2(v0, v1), pk2(v2, v3));
        }
    }

    // re-read inter rows as x^T B-fragments (b128, same-wave rows, no barrier needed)
    bf16x8 aI[3][4];
    #pragma unroll
    for (int i = 0; i < 3; ++i) {
        const int row = (w * 3 + i) * 16 + m;
        #pragma unroll
        for (int kt = 0; kt < 4; ++kt)
            aI[i][kt] = *(const bf16x8*)(inter_s + row * STR + kt * 32 + q * 8);
    }

    // phase 2: gate/mag, in-place overwrite with sigmoid*softplus
    #pragma unroll
    for (int ct = 0; ct < 8; ++ct) {
        f32x4 Cg[3], Cm[3];
        #pragma unroll
        for (int i = 0; i < 3; ++i) {
            Cg[i] = (f32x4){0.f, 0.f, 0.f, 0.f};
            Cm[i] = (f32x4){0.f, 0.f, 0.f, 0.f};
        }
        #pragma unroll
        for (int kt = 0; kt < 4; ++kt) {
            const bf16x8 gfr = *(const bf16x8*)(Wg + ((kt * 8 + ct) * 64 + lane) * 8);
            const bf16x8 mfr = *(const bf16x8*)(Wm + ((kt * 8 + ct) * 64 + lane) * 8);
            #pragma unroll
            for (int i = 0; i < 3; ++i) {
                Cg[i] = __builtin_amdgcn_mfma_f32_16x16x32_bf16(gfr, aI[i][kt], Cg[i], 0, 0, 0);
                Cm[i] = __builtin_amdgcn_mfma_f32_16x16x32_bf16(mfr, aI[i][kt], Cm[i], 0, 0, 0);
            }
        }
        const float4 bgv = *(const float4*)(bg + ct * 16 + q * 4);
        const float4 bmv = *(const float4*)(bm + ct * 16 + q * 4);
        #pragma unroll
        for (int i = 0; i < 3; ++i) {
            const float v0 = sigmoid_f(Cg[i][0] + bgv.x) * softplus_f(Cm[i][0] + bmv.x);
            const float v1 = sigmoid_f(Cg[i][1] + bgv.y) * softplus_f(Cm[i][1] + bmv.y);
            const float v2 = sigmoid_f(Cg[i][2] + bgv.z) * softplus_f(Cm[i][2] + bmv.z);
            const float v3 = sigmoid_f(Cg[i][3] + bgv.w) * softplus_f(Cm[i][3] + bmv.w);
            *(uint2*)(inter_s + (w * 48 + i * 16 + m) * STR + ct * 16 + q * 4) =
                make_uint2(pk2(v0, v1), pk2(v2, v3));
        }
    }
    __syncthreads();

    // neighbor-sum + LayerNorm + residual
    {
        const int a = tid >> 4;
        const int cg = tid & 15;
        float s8[8];
        #pragma unroll
        for (int j = 0; j < 8; ++j) s8[j] = 0.f;
        #pragma unroll
        for (int nb = 0; nb < 12; ++nb) {
            const bf16x8 p = *(const bf16x8*)(inter_s + (a * 12 + nb) * STR + cg * 8);
            #pragma unroll
            for (int j = 0; j < 8; ++j) s8[j] += bf2f(p[j]);
        }
        float lsum = 0.f, lsq = 0.f;
        #pragma unroll
        for (int j = 0; j < 8; ++j) { lsum += s8[j]; lsq += s8[j] * s8[j]; }
        #pragma unroll
        for (int off = 1; off < 16; off <<= 1) {
            lsum += __shfl_xor(lsum, off, 64);
            lsq  += __shfl_xor(lsq,  off, 64);
        }
        const float mu = lsum * (1.0f / FD);
        float var = lsq * (1.0f / FD) - mu * mu;
        var = fmaxf(var, 0.0f);
        const float inv = rsqrtf(var + 1e-6f);
        const long xb = ((long)(a0 + a) << 7) + cg * 8;
        float xv[8], sc[4], sc2[4], bb[4], bb2[4];
        *(float4*)&xv[0] = *(const float4*)(x_in + xb);
        *(float4*)&xv[4] = *(const float4*)(x_in + xb + 4);
        *(float4*)&sc[0]  = *(const float4*)(lns + cg * 8);
        *(float4*)&sc2[0] = *(const float4*)(lns + cg * 8 + 4);
        *(float4*)&bb[0]  = *(const float4*)(lnb + cg * 8);
        *(float4*)&bb2[0] = *(const float4*)(lnb + cg * 8 + 4);
        float o[8];
        #pragma unroll
        for (int j = 0; j < 4; ++j) {
            o[j]     = xv[j]     + (s8[j]     - mu) * inv * sc[j]  + bb[j];
            o[j + 4] = xv[j + 4] + (s8[j + 4] - mu) * inv * sc2[j] + bb2[j];
        }
        BF8 ob;
        ob.u[0] = pk2(o[0], o[1]); ob.u[1] = pk2(o[2], o[3]);
        ob.u[2] = pk2(o[4], o[5]); ob.u[3] = pk2(o[6], o[7]);
        *(float4*)(x_out + xb)     = make_float4(o[0], o[1], o[2], o[3]);
        *(float4*)(x_out + xb + 4) = make_float4(o[4], o[5], o[6], o[7]);
        *(bf16x8*)(xbf_out + xb)   = ob.v;
    }
}

// ---------------- readout MFMA: 64 atoms/block, 4 waves ----------------
__global__ __launch_bounds__(256) void readout_mfma_kernel(
    const short* __restrict__ xbf, const short* __restrict__ whf,
    const float* __restrict__ bh, const float* __restrict__ Wo,
    const float* __restrict__ bo, float* __restrict__ out)
{
    const int tid = threadIdx.x;
    const int w = tid >> 6, lane = tid & 63;
    const int q = lane >> 4, m = lane & 15;
    const int a0 = blockIdx.x * 64;
    const int arow = a0 + w * 16 + m;

    bf16x8 aX[4];
    #pragma unroll
    for (int kt = 0; kt < 4; ++kt)
        aX[kt] = *(const bf16x8*)(xbf + ((long)arow << 7) + kt * 32 + q * 8);

    float e[4] = {0.f, 0.f, 0.f, 0.f};
    #pragma unroll
    for (int nt = 0; nt < 16; ++nt) {
        f32x4 C = {0.f, 0.f, 0.f, 0.f};
        #pragma unroll
        for (int kt = 0; kt < 4; ++kt)
            C = __builtin_amdgcn_mfma_f32_16x16x32_bf16(
                    aX[kt], *(const bf16x8*)(whf + ((kt * 16 + nt) * 64 + lane) * 8), C, 0, 0, 0);
        const int col = nt * 16 + m;
        const float bhv = bh[col], wov = Wo[col];
        #pragma unroll
        for (int r = 0; r < 4; ++r)
            e[r] += softplus_f(C[r] + bhv) * wov;
    }
    float esum = e[0] + e[1] + e[2] + e[3];
    #pragma unroll
    for (int off = 32; off > 0; off >>= 1)
        esum += __shfl_xor(esum, off, 64);
    if (lane == 0)
        atomicAdd(&out[a0 / APC], esum + 16.0f * bo[0]);
}

__global__ void zero_out_kernel(float* __restrict__ out) {
    if (threadIdx.x < NCRY) out[threadIdx.x] = 0.0f;
}

extern "C" void kernel_launch(void* const* d_in, const int* in_sizes, int n_in,
                              void* d_out, int out_size, void* d_ws, size_t ws_size,
                              hipStream_t stream) {
    const float* atom_fea = (const float*)d_in[0];
    const float* nbr_fea  = (const float*)d_in[1];
    const int*   nbr_idx  = (const int*)d_in[2];
    const float* W_embed  = (const float*)d_in[3];
    const float* b_embed  = (const float*)d_in[4];
    const float* W_center = (const float*)d_in[5];
    const float* b_center = (const float*)d_in[6];
    const float* W_nbr    = (const float*)d_in[7];
    const float* b_nbr    = (const float*)d_in[8];
    const float* W_edge   = (const float*)d_in[9];
    const float* b_edge   = (const float*)d_in[10];
    const float* W_gate   = (const float*)d_in[11];
    const float* b_gate   = (const float*)d_in[12];
    const float* W_mag    = (const float*)d_in[13];
    const float* b_mag    = (const float*)d_in[14];
    const float* ln_scale = (const float*)d_in[15];
    const float* ln_bias  = (const float*)d_in[16];
    const float* W_h      = (const float*)d_in[17];
    const float* b_h      = (const float*)d_in[18];
    const float* W_out    = (const float*)d_in[19];
    const float* b_out    = (const float*)d_in[20];

    float* out = (float*)d_out;
    const size_t NX = (size_t)N_TOT * FD;
    float* xA = (float*)d_ws;
    float* xB = xA + NX;
    short* xbfA = (short*)(xB + NX);
    short* xbfB = xbfA + NX;
    short* wfrag = xbfB + NX;

    swizzle_kernel<<<130, 256, 0, stream>>>(W_center, W_nbr, W_edge, W_gate, W_mag,
                                            W_embed, W_h, wfrag);
    embed_mfma_kernel<<<N_TOT / 64, 256, 0, stream>>>(
        atom_fea, wfrag + 3 * WF_PER_LAYER, b_embed, xA, xbfA);

    const float* xi = xA; float* xo = xB;
    const short* xbi = xbfA; short* xbo = xbfB;
    for (int l = 0; l < 3; ++l) {
        conv_mfma_kernel<<<N_TOT / 16, 256, 0, stream>>>(
            xi, xbi, xo, xbo, nbr_fea, nbr_idx,
            wfrag + (size_t)l * WF_PER_LAYER,
            b_center + (size_t)l * FD, b_nbr + (size_t)l * FD,
            b_edge + (size_t)l * FD, b_gate + (size_t)l * FD,
            b_mag + (size_t)l * FD,
            ln_scale + (size_t)l * FD, ln_bias + (size_t)l * FD);
        const float* tf = xo; xo = (float*)xi; xi = tf;
        const short* tb = xbo; xbo = (short*)xbi; xbi = tb;
    }

    zero_out_kernel<<<1, 128, 0, stream>>>(out);
    readout_mfma_kernel<<<N_TOT / 64, 256, 0, stream>>>(
        xbi, wfrag + 3 * WF_PER_LAYER + WF_EMBED, b_h, W_out, b_out, out);
}